// Round 1
// baseline (439.547 us; speedup 1.0000x reference)
//
#include <hip/hip_runtime.h>
#include <hip/hip_bf16.h>
#include <cstdint>

#define B_    4
#define S_    2048
#define D_    1024
#define SCALE 0.03125f     // 1/sqrt(1024)
#define NEG_BIG -1e9f

typedef __attribute__((ext_vector_type(8))) short short8;   // 8 bf16 (4 VGPRs)
typedef __attribute__((ext_vector_type(4))) float f32x4;    // MFMA C/D frag

__device__ __forceinline__ ushort f2bf(float f) {
  uint32_t u = __float_as_uint(f);
  u += 0x7fffu + ((u >> 16) & 1u);   // round-to-nearest-even
  return (ushort)(u >> 16);
}

// ---------------- kernel 0a: K fp32 -> bf16 ----------------
__global__ void convert_k(const float* __restrict__ K, ushort* __restrict__ Kb) {
  size_t i = ((size_t)blockIdx.x * 256 + threadIdx.x) * 8;
  float4 a = *(const float4*)(K + i);
  float4 c = *(const float4*)(K + i + 4);
  uint4 w;
  w.x = (uint)f2bf(a.x) | ((uint)f2bf(a.y) << 16);
  w.y = (uint)f2bf(a.z) | ((uint)f2bf(a.w) << 16);
  w.z = (uint)f2bf(c.x) | ((uint)f2bf(c.y) << 16);
  w.w = (uint)f2bf(c.z) | ((uint)f2bf(c.w) << 16);
  *(uint4*)(Kb + i) = w;
}

// ---------------- kernel 0b: V fp32 -> bf16 transposed Vt[b][d][s] ----------------
__global__ void transpose_v(const float* __restrict__ V, ushort* __restrict__ Vt) {
  __shared__ ushort tile[32][33];
  int x = threadIdx.x & 31, y = threadIdx.x >> 5;
  int s0 = blockIdx.x * 32, d0 = blockIdx.y * 32, b = blockIdx.z;
  const float* src = V + ((size_t)b * S_ + s0) * D_ + d0;
  for (int i = 0; i < 4; ++i) {
    int sl = y + i * 8;
    tile[sl][x] = f2bf(src[(size_t)sl * D_ + x]);
  }
  __syncthreads();
  ushort* dst = Vt + ((size_t)b * D_ + d0) * S_ + s0;
  for (int i = 0; i < 4; ++i) {
    int dl = y + i * 8;
    dst[(size_t)dl * S_ + x] = tile[x][dl];
  }
}

// ---------------- kernel 1: fused flash attention ----------------
// grid 256 blocks, 512 threads (8 waves). Block: one batch, 32 query rows.
// Wave w owns output D-slice [128w, 128w+128).
__launch_bounds__(512, 2)
__global__ void flash_attn(const float* __restrict__ Q, const ushort* __restrict__ Kb,
                           const ushort* __restrict__ Vt, const int* __restrict__ mask,
                           float* __restrict__ Out) {
  // XCD swizzle: batch b -> XCD pair {2b, 2b+1} so each batch's 8MB bf16 K/V
  // lives in 2 XCDs' combined 8MB L2.
  int i = blockIdx.x;
  int b  = (i & 7) >> 1;
  int qt = ((i >> 3) << 1) | (i & 1);
  int q0 = qt * 32;

  int tid  = threadIdx.x;
  int lane = tid & 63;
  int wave = tid >> 6;      // 0..7
  int quad = lane >> 4;     // 0..3
  int l16  = lane & 15;

  __shared__ __align__(16) float  sPart[8][32][34];  // partial S per wave, pad 34
  __shared__ __align__(16) ushort sP[32][56];        // P bf16, stride 56 (112B, 16-aligned, 2-way banks)
  __shared__ float sM[32], sL[32], sAlpha[32];

  if (tid < 32) { sM[tid] = -3.0e38f; sL[tid] = 0.f; }

  // ---- preload Q fragments (persist across key loop) ----
  // A-frag layout: A[m = lane&15][k = quad*8 + j]
  short8 qf[2][4];
  {
    const float* qbase = Q + (size_t)(b * S_ + q0) * D_;
    for (int mt = 0; mt < 2; ++mt)
      for (int kc = 0; kc < 4; ++kc) {
        const float* p = qbase + (size_t)(mt * 16 + l16) * D_ + wave * 128 + kc * 32 + quad * 8;
        float4 a = *(const float4*)p;
        float4 c = *(const float4*)(p + 4);
        short8 v;
        v[0] = (short)f2bf(a.x); v[1] = (short)f2bf(a.y);
        v[2] = (short)f2bf(a.z); v[3] = (short)f2bf(a.w);
        v[4] = (short)f2bf(c.x); v[5] = (short)f2bf(c.y);
        v[6] = (short)f2bf(c.z); v[7] = (short)f2bf(c.w);
        qf[mt][kc] = v;
      }
  }

  f32x4 o[2][8];
  for (int mt = 0; mt < 2; ++mt)
    for (int nt = 0; nt < 8; ++nt)
      o[mt][nt] = (f32x4){0.f, 0.f, 0.f, 0.f};

  __syncthreads();

  int srow = tid >> 4;          // stats: row 0..31 (16 threads each)
  int skp  = (tid & 15) * 2;    // stats: 2 keys per thread

  for (int kt = 0; kt < 64; ++kt) {
    int k0 = kt * 32;

    // ---- QK^T partial over this wave's 128-dim slice ----
    f32x4 sc[2][2];
    for (int mt = 0; mt < 2; ++mt)
      for (int nt = 0; nt < 2; ++nt)
        sc[mt][nt] = (f32x4){0.f, 0.f, 0.f, 0.f};
    const ushort* kbase = Kb + (size_t)(b * S_ + k0 + l16) * D_ + wave * 128 + quad * 8;
    for (int kc = 0; kc < 4; ++kc) {
      short8 kb0 = *(const short8*)(kbase + kc * 32);
      short8 kb1 = *(const short8*)(kbase + (size_t)16 * D_ + kc * 32);
      sc[0][0] = __builtin_amdgcn_mfma_f32_16x16x32_bf16(qf[0][kc], kb0, sc[0][0], 0, 0, 0);
      sc[1][0] = __builtin_amdgcn_mfma_f32_16x16x32_bf16(qf[1][kc], kb0, sc[1][0], 0, 0, 0);
      sc[0][1] = __builtin_amdgcn_mfma_f32_16x16x32_bf16(qf[0][kc], kb1, sc[0][1], 0, 0, 0);
      sc[1][1] = __builtin_amdgcn_mfma_f32_16x16x32_bf16(qf[1][kc], kb1, sc[1][1], 0, 0, 0);
    }
    // C layout: col = lane&15, row = quad*4 + r
    for (int mt = 0; mt < 2; ++mt)
      for (int nt = 0; nt < 2; ++nt)
        for (int r = 0; r < 4; ++r)
          sPart[wave][mt * 16 + quad * 4 + r][nt * 16 + l16] = sc[mt][nt][r];
    __syncthreads();

    // ---- online softmax stats (all 512 threads; 16 threads per row) ----
    {
      float s0 = 0.f, s1 = 0.f;
      for (int w = 0; w < 8; ++w) {
        const float* p = &sPart[w][srow][skp];
        s0 += p[0]; s1 += p[1];
      }
      int mk0 = mask[b * S_ + k0 + skp];
      int mk1 = mask[b * S_ + k0 + skp + 1];
      float l0 = s0 * SCALE + (mk0 ? NEG_BIG : 0.f);
      float l1 = s1 * SCALE + (mk1 ? NEG_BIG : 0.f);
      float tmax = fmaxf(l0, l1);
      for (int off = 1; off <= 8; off <<= 1) tmax = fmaxf(tmax, __shfl_xor(tmax, off));
      float mold = sM[srow];
      float mnew = fmaxf(mold, tmax);
      float p0 = __expf(l0 - mnew), p1 = __expf(l1 - mnew);
      float ts = p0 + p1;
      for (int off = 1; off <= 8; off <<= 1) ts += __shfl_xor(ts, off);
      float alpha = __expf(mold - mnew);
      if ((tid & 15) == 0) {
        sM[srow]     = mnew;
        sL[srow]     = sL[srow] * alpha + ts;
        sAlpha[srow] = alpha;
      }
      uint32_t pw = (uint32_t)f2bf(p0) | ((uint32_t)f2bf(p1) << 16);
      *(uint32_t*)&sP[srow][skp] = pw;
    }
    __syncthreads();

    // ---- rescale O by alpha, then O += P @ V-slice ----
    for (int mt = 0; mt < 2; ++mt)
      for (int r = 0; r < 4; ++r) {
        float a = sAlpha[mt * 16 + quad * 4 + r];
        for (int nt = 0; nt < 8; ++nt) o[mt][nt][r] *= a;
      }
    short8 ap0 = *(const short8*)&sP[l16][quad * 8];
    short8 ap1 = *(const short8*)&sP[16 + l16][quad * 8];
    // B-frag of V: B[k][n] = V[key k][col n]; Vt[b][col][key] -> 8 contiguous keys
    const ushort* vbase = Vt + ((size_t)b * D_ + wave * 128 + l16) * S_ + k0 + quad * 8;
    for (int nt = 0; nt < 8; ++nt) {
      short8 bv = *(const short8*)(vbase + (size_t)nt * 16 * S_);
      o[0][nt] = __builtin_amdgcn_mfma_f32_16x16x32_bf16(ap0, bv, o[0][nt], 0, 0, 0);
      o[1][nt] = __builtin_amdgcn_mfma_f32_16x16x32_bf16(ap1, bv, o[1][nt], 0, 0, 0);
    }
    // no barrier needed here: next iter's sPart writes are fenced by SYNC1,
    // next iter's sP writes by its own post-SYNC1 position.
  }

  // ---- epilogue: divide by l, store fp32 ----
  float invl[2][4];
  for (int mt = 0; mt < 2; ++mt)
    for (int r = 0; r < 4; ++r)
      invl[mt][r] = 1.0f / sL[mt * 16 + quad * 4 + r];
  float* obase = Out + (size_t)(b * S_ + q0) * D_ + wave * 128 + l16;
  for (int mt = 0; mt < 2; ++mt)
    for (int r = 0; r < 4; ++r) {
      float* po = obase + (size_t)(mt * 16 + quad * 4 + r) * D_;
      float s = invl[mt][r];
      for (int nt = 0; nt < 8; ++nt) po[nt * 16] = o[mt][nt][r] * s;
    }
}

extern "C" void kernel_launch(void* const* d_in, const int* in_sizes, int n_in,
                              void* d_out, int out_size, void* d_ws, size_t ws_size,
                              hipStream_t stream) {
  const float* Q   = (const float*)d_in[0];
  const float* K   = (const float*)d_in[1];
  const float* V   = (const float*)d_in[2];
  const int*  mask = (const int*)d_in[3];
  float* Out = (float*)d_out;

  // workspace: Kb (bf16, 16.78MB) then Vt (bf16 transposed, 16.78MB)
  ushort* Kb = (ushort*)d_ws;
  ushort* Vt = Kb + (size_t)B_ * S_ * D_;

  convert_k<<<4096, 256, 0, stream>>>(K, Kb);
  transpose_v<<<dim3(64, 32, 4), 256, 0, stream>>>(V, Vt);
  flash_attn<<<256, 512, 0, stream>>>(Q, Kb, Vt, mask, Out);
}